// Round 3
// baseline (544.105 us; speedup 1.0000x reference)
//
#include <hip/hip_runtime.h>
#include <hip/hip_bf16.h>

typedef __attribute__((ext_vector_type(4))) float f32x4;
typedef __attribute__((ext_vector_type(8))) __bf16 bf16x8;

static constexpr int JOBS   = 200000 / 16;  // 12500 wave-jobs, 16 atoms each
static constexpr int BLOCKS = JOBS / 4;     // 4 waves per block

// ---------------- helpers ----------------
__device__ __forceinline__ float fsilu(float x) {
  return x * __builtin_amdgcn_rcpf(1.f + __expf(-x));
}
__device__ __forceinline__ unsigned short f2bu(float f) {
  return __builtin_bit_cast(unsigned short, (__bf16)f);
}
// XOR swizzle (ushort-index): spreads rows across 16B chunks, G4-style
__device__ __forceinline__ int SW(int row, int col) { return col ^ ((row & 7) << 3); }

__device__ __forceinline__ bf16x8 cvt8(const float* __restrict__ p) {
  bf16x8 r;
#pragma unroll
  for (int i = 0; i < 8; ++i) r[i] = (__bf16)p[i];
  return r;
}
__device__ __forceinline__ bf16x8 ldfrag(const float4* __restrict__ p) {
  float4 t = *p;
  return __builtin_bit_cast(bf16x8, t);
}
// read 8 bf16 (16B) from LDS, expand to f32
__device__ __forceinline__ void ld8(const unsigned short* __restrict__ p, float* dst) {
  uint4 v = *reinterpret_cast<const uint4*>(p);
  unsigned uu[4] = {v.x, v.y, v.z, v.w};
#pragma unroll
  for (int k = 0; k < 4; ++k) {
    dst[2 * k]     = __uint_as_float(uu[k] << 16);
    dst[2 * k + 1] = __uint_as_float(uu[k] & 0xffff0000u);
  }
}

// ---------------- prep: pack weights into MFMA B-fragment order (bf16) ----------------
// frag elem (lane, e): n = ot*16 + (lane&15), k = kb*32 + (lane>>4)*8 + e
__global__ void prep_kernel(const float* __restrict__ Wmix1,
                            const float* __restrict__ W1_1,
                            const float* __restrict__ W2_1,
                            unsigned short* __restrict__ ws) {
  const int tid = threadIdx.x;
  // B1: Wmix1 (128x128): 8 ot * 4 kb
  for (int idx = tid; idx < 16384; idx += 256) {
    int e = idx & 7, ln = (idx >> 3) & 63, f = idx >> 9;
    int kb = f & 3, ot = f >> 2;
    int k = kb * 32 + (ln >> 4) * 8 + e;
    int o = ot * 16 + (ln & 15);
    ws[idx] = f2bu(Wmix1[k * 128 + o]);
  }
  // B2: W1_1 (192x64): 4 ot * 6 kb, at ushort offset 16384
  for (int idx = tid; idx < 12288; idx += 256) {
    int e = idx & 7, ln = (idx >> 3) & 63, f = idx >> 9;
    int kb = f % 6, ot = f / 6;
    int k = kb * 32 + (ln >> 4) * 8 + e;
    int n = ot * 16 + (ln & 15);
    ws[16384 + idx] = f2bu(W1_1[k * 64 + n]);
  }
  // B3: W2_1 (64x128): 8 ot * 2 kb, at ushort offset 28672
  for (int idx = tid; idx < 8192; idx += 256) {
    int e = idx & 7, ln = (idx >> 3) & 63, f = idx >> 9;
    int kb = f & 1, ot = f >> 1;
    int k = kb * 32 + (ln >> 4) * 8 + e;
    int n = ot * 16 + (ln & 15);
    ws[28672 + idx] = f2bu(W2_1[k * 128 + n]);
  }
}

// ---------------- fused main kernel: one 16-atom job per wave ----------------
__global__ __launch_bounds__(256, 3)
void fused_kernel(const float* __restrict__ pos,
                  const float* __restrict__ srep,
                  const float* __restrict__ vrep,
                  const float4* __restrict__ wsf,
                  const float* __restrict__ b1_1,
                  const float* __restrict__ b2_1,
                  const float* __restrict__ Wmix2,
                  const float* __restrict__ W1_2,
                  const float* __restrict__ b1_2,
                  const float* __restrict__ W2_2,
                  const float* __restrict__ b2_2,
                  const float* __restrict__ Wd1,
                  const float* __restrict__ bd1,
                  const float* __restrict__ Wd2,
                  const float* __restrict__ bd2,
                  float* __restrict__ out) {
  __shared__ __align__(16) unsigned short smem[4 * 5120];  // 10 KiB per wave, wave-private
  const int tid  = threadIdx.x;
  const int lane = tid & 63;
  const int wv   = tid >> 6;
  const int r    = lane & 15;  // A row / D col index
  const int g    = lane >> 4;  // k-group / D row-group
  const int a0   = (blockIdx.x * 4 + wv) * 16;

  unsigned short* vWl = smem + wv * 5120;  // [3][16][64] bf16  (3072 ushorts)
  unsigned short* vVn = vWl + 3072;        // [16][64]          (1024)
  unsigned short* Hh  = vWl + 4096;        // [16][64]          (1024)
  unsigned short* SGl = vWl + 3072;        // [16][128] aliases vVn+Hh (safe: in-order DS, reads precede writes)

  // ============ GEMM1: vmix[3*16,128] = v * Wmix1 ============
  bf16x8 A1[3][4];
  {
    const float* vp = vrep + (size_t)(a0 + r) * 384;
#pragma unroll
    for (int c = 0; c < 3; ++c)
#pragma unroll
      for (int kb = 0; kb < 4; ++kb)
        A1[c][kb] = cvt8(vp + c * 128 + kb * 32 + g * 8);
  }
#pragma unroll
  for (int ot = 0; ot < 8; ++ot) {
    bf16x8 B[4];
#pragma unroll
    for (int kb = 0; kb < 4; ++kb)
      B[kb] = ldfrag(wsf + (ot * 4 + kb) * 64 + lane);
    f32x4 ac0 = {0.f, 0.f, 0.f, 0.f}, ac1 = ac0, ac2 = ac0;
#pragma unroll
    for (int kb = 0; kb < 4; ++kb) {
      ac0 = __builtin_amdgcn_mfma_f32_16x16x32_bf16(A1[0][kb], B[kb], ac0, 0, 0, 0);
      ac1 = __builtin_amdgcn_mfma_f32_16x16x32_bf16(A1[1][kb], B[kb], ac1, 0, 0, 0);
      ac2 = __builtin_amdgcn_mfma_f32_16x16x32_bf16(A1[2][kb], B[kb], ac2, 0, 0, 0);
    }
    if (ot < 4) {  // vV half -> per-atom norm over c
#pragma unroll
      for (int i = 0; i < 4; ++i) {
        int row = g * 4 + i;
        float nv = sqrtf(ac0[i] * ac0[i] + ac1[i] * ac1[i] + ac2[i] * ac2[i]);
        vVn[row * 64 + SW(row, ot * 16 + r)] = f2bu(nv);
      }
    } else {  // vW half -> keep for gating
      int col = (ot - 4) * 16 + r;
#pragma unroll
      for (int i = 0; i < 4; ++i) {
        int row = g * 4 + i;
        int sc  = SW(row, col);
        vWl[       row * 64 + sc] = f2bu(ac0[i]);
        vWl[1024 + row * 64 + sc] = f2bu(ac1[i]);
        vWl[2048 + row * 64 + sc] = f2bu(ac2[i]);
      }
    }
  }

  // ============ GEMM2: x[16,64] = silu([s, vVn] * W1_1 + b1_1) ============
  bf16x8 A2[6];
  {
    const float* sp = srep + (size_t)(a0 + r) * 128;
#pragma unroll
    for (int kb = 0; kb < 4; ++kb)
      A2[kb] = cvt8(sp + kb * 32 + g * 8);
#pragma unroll
    for (int kb = 0; kb < 2; ++kb) {
      int col0 = kb * 32 + g * 8;
      A2[4 + kb] = *reinterpret_cast<const bf16x8*>(vVn + r * 64 + SW(r, col0));
    }
  }
  float b1v[4];
#pragma unroll
  for (int ot = 0; ot < 4; ++ot) b1v[ot] = b1_1[ot * 16 + r];
#pragma unroll
  for (int ot = 0; ot < 4; ++ot) {
    bf16x8 B[6];
#pragma unroll
    for (int kb = 0; kb < 6; ++kb)
      B[kb] = ldfrag(wsf + 2048 + (ot * 6 + kb) * 64 + lane);
    f32x4 ac = {0.f, 0.f, 0.f, 0.f};
#pragma unroll
    for (int kb = 0; kb < 6; ++kb)
      ac = __builtin_amdgcn_mfma_f32_16x16x32_bf16(A2[kb], B[kb], ac, 0, 0, 0);
#pragma unroll
    for (int i = 0; i < 4; ++i) {
      int row = g * 4 + i;
      Hh[row * 64 + SW(row, ot * 16 + r)] = f2bu(fsilu(ac[i] + b1v[ot]));
    }
  }

  // ============ GEMM3: x2[16,128] = h * W2_1 + b2_1 ============
  bf16x8 A3[2];
#pragma unroll
  for (int kb = 0; kb < 2; ++kb) {
    int col0 = kb * 32 + g * 8;
    A3[kb] = *reinterpret_cast<const bf16x8*>(Hh + r * 64 + SW(r, col0));
  }
  float b2v[8];
#pragma unroll
  for (int ot = 0; ot < 8; ++ot) b2v[ot] = b2_1[ot * 16 + r];
#pragma unroll
  for (int ot = 0; ot < 8; ++ot) {
    bf16x8 B[2];
#pragma unroll
    for (int kb = 0; kb < 2; ++kb)
      B[kb] = ldfrag(wsf + 3584 + (ot * 2 + kb) * 64 + lane);
    f32x4 ac = {0.f, 0.f, 0.f, 0.f};
#pragma unroll
    for (int kb = 0; kb < 2; ++kb)
      ac = __builtin_amdgcn_mfma_f32_16x16x32_bf16(A3[kb], B[kb], ac, 0, 0, 0);
#pragma unroll
    for (int i = 0; i < 4; ++i) {
      int row = g * 4 + i;
      float x = ac[i] + b2v[ot];
      if (ot < 4) {
        SGl[row * 128 + SW(row, ot * 16 + r)] = f2bu(fsilu(x));        // s_out
      } else {
        SGl[row * 128 + SW(row, 64 + (ot - 4) * 16 + r)] = f2bu(x);    // gate
      }
    }
  }

  // ============ epilogue: block2 + final MLP, 4 lanes per atom ============
  const int aq   = lane >> 2;  // local atom 0..15
  const int q    = lane & 3;   // o'-quarter
  const int atom = a0 + aq;

  float p00 = 0.f, p01 = 0.f, p02 = 0.f, p10 = 0.f, p11 = 0.f, p12 = 0.f, sw = 0.f;
  const float2* Wm2 = reinterpret_cast<const float2*>(Wmix2);
#pragma unroll
  for (int h = 0; h < 2; ++h) {
    float so[8], ga[8], v0[8], v1[8], v2[8];
    int col = q * 16 + h * 8;
    ld8(SGl +        aq * 128 + SW(aq, col),      so);
    ld8(SGl +        aq * 128 + SW(aq, 64 + col), ga);
    ld8(vWl +        aq * 64  + SW(aq, col),      v0);
    ld8(vWl + 1024 + aq * 64  + SW(aq, col),      v1);
    ld8(vWl + 2048 + aq * 64  + SW(aq, col),      v2);
#pragma unroll
    for (int i = 0; i < 8; ++i) {
      int o = col + i;
      float2 wm = Wm2[o];
      float t0 = ga[i] * v0[i], t1 = ga[i] * v1[i], t2 = ga[i] * v2[i];
      p00 += t0 * wm.x; p01 += t1 * wm.x; p02 += t2 * wm.x;
      p10 += t0 * wm.y; p11 += t1 * wm.y; p12 += t2 * wm.y;
      sw  += so[i] * W1_2[o];
    }
  }
#pragma unroll
  for (int m = 1; m <= 2; m <<= 1) {
    p00 += __shfl_xor(p00, m); p01 += __shfl_xor(p01, m); p02 += __shfl_xor(p02, m);
    p10 += __shfl_xor(p10, m); p11 += __shfl_xor(p11, m); p12 += __shfl_xor(p12, m);
    sw  += __shfl_xor(sw,  m);
  }
  float vn2 = sqrtf(p00 * p00 + p01 * p01 + p02 * p02);
  float x1  = fsilu(sw + vn2 * W1_2[64] + b1_2[0]);
  float s2  = x1 * W2_2[0] + b2_2[0];
  float g2  = x1 * W2_2[1] + b2_2[1];
  float feat[7];
  feat[0] = g2 * p10; feat[1] = g2 * p11; feat[2] = g2 * p12;
  feat[3] = pos[atom * 3 + 0];
  feat[4] = pos[atom * 3 + 1];
  feat[5] = pos[atom * 3 + 2];
  feat[6] = s2;
  float o0 = bd2[0], o1 = bd2[1], o2 = bd2[2];
#pragma unroll
  for (int j = 0; j < 10; ++j) {
    float hp = bd1[j];
#pragma unroll
    for (int i = 0; i < 7; ++i) hp += feat[i] * Wd1[i * 10 + j];
    float hj = fsilu(hp);
    o0 += hj * Wd2[j * 3 + 0];
    o1 += hj * Wd2[j * 3 + 1];
    o2 += hj * Wd2[j * 3 + 2];
  }
  if (q < 3) {
    out[atom * 3 + q] = (q == 0) ? o0 : ((q == 1) ? o1 : o2);
  }
}

extern "C" void kernel_launch(void* const* d_in, const int* in_sizes, int n_in,
                              void* d_out, int out_size, void* d_ws, size_t ws_size,
                              hipStream_t stream) {
  const float* pos   = (const float*)d_in[0];
  const float* srep  = (const float*)d_in[1];
  const float* vrep  = (const float*)d_in[2];
  const float* Wmix1 = (const float*)d_in[4];
  const float* W1_1  = (const float*)d_in[5];
  const float* b1_1  = (const float*)d_in[6];
  const float* W2_1  = (const float*)d_in[7];
  const float* b2_1  = (const float*)d_in[8];
  const float* Wmix2 = (const float*)d_in[9];
  const float* W1_2  = (const float*)d_in[10];
  const float* b1_2  = (const float*)d_in[11];
  const float* W2_2  = (const float*)d_in[12];
  const float* b2_2  = (const float*)d_in[13];
  const float* Wd1   = (const float*)d_in[14];
  const float* bd1   = (const float*)d_in[15];
  const float* Wd2   = (const float*)d_in[16];
  const float* bd2   = (const float*)d_in[17];

  hipLaunchKernelGGL(prep_kernel, dim3(1), dim3(256), 0, stream,
                     Wmix1, W1_1, W2_1, (unsigned short*)d_ws);
  hipLaunchKernelGGL(fused_kernel, dim3(BLOCKS), dim3(256), 0, stream,
                     pos, srep, vrep, (const float4*)d_ws,
                     b1_1, b2_1, Wmix2, W1_2, b1_2, W2_2, b2_2,
                     Wd1, bd1, Wd2, bd2, (float*)d_out);
}

// Round 4
// 519.781 us; speedup vs baseline: 1.0468x; 1.0468x over previous
//
#include <hip/hip_runtime.h>
#include <hip/hip_bf16.h>

typedef __attribute__((ext_vector_type(4))) float f32x4;
typedef __attribute__((ext_vector_type(8))) __bf16 bf16x8;

static constexpr int JOBS   = 200000 / 16;  // 12500 wave-jobs, 16 atoms each
static constexpr int BLOCKS = JOBS / 4;     // 4 waves per block

// ---------------- helpers ----------------
__device__ __forceinline__ float fsilu(float x) {
  return x * __builtin_amdgcn_rcpf(1.f + __expf(-x));
}
__device__ __forceinline__ unsigned short f2bu(float f) {
  return __builtin_bit_cast(unsigned short, (__bf16)f);
}
// XOR swizzle (ushort-index): spreads rows across 16B chunks, G4-style
__device__ __forceinline__ int SW(int row, int col) { return col ^ ((row & 7) << 3); }

// explicit 2x dwordx4 load + pack to bf16x8 (do NOT rely on SLP vectorization, G13)
__device__ __forceinline__ bf16x8 cvt8v(const float* __restrict__ p) {
  const float4* q = reinterpret_cast<const float4*>(p);
  float4 x = q[0], y = q[1];
  bf16x8 r;
  r[0] = (__bf16)x.x; r[1] = (__bf16)x.y; r[2] = (__bf16)x.z; r[3] = (__bf16)x.w;
  r[4] = (__bf16)y.x; r[5] = (__bf16)y.y; r[6] = (__bf16)y.z; r[7] = (__bf16)y.w;
  return r;
}
__device__ __forceinline__ bf16x8 ldfrag(const float4* __restrict__ p) {
  float4 t = *p;
  return __builtin_bit_cast(bf16x8, t);
}
// read 8 bf16 (16B) from LDS, expand to f32
__device__ __forceinline__ void ld8(const unsigned short* __restrict__ p, float* dst) {
  uint4 v = *reinterpret_cast<const uint4*>(p);
  unsigned uu[4] = {v.x, v.y, v.z, v.w};
#pragma unroll
  for (int k = 0; k < 4; ++k) {
    dst[2 * k]     = __uint_as_float(uu[k] << 16);
    dst[2 * k + 1] = __uint_as_float(uu[k] & 0xffff0000u);
  }
}

// ---------------- prep: pack weights into MFMA B-fragment order (bf16) ----------------
// frag elem (lane, e): n = ot*16 + (lane&15), k = kb*32 + (lane>>4)*8 + e
// Parallelized across 36 blocks (was 1 block = latency-serialized tail).
__global__ void prep_kernel(const float* __restrict__ Wmix1,
                            const float* __restrict__ W1_1,
                            const float* __restrict__ W2_1,
                            unsigned short* __restrict__ ws) {
  const int tid = blockIdx.x * blockDim.x + threadIdx.x;
  const int stp = gridDim.x * blockDim.x;
  // B1: Wmix1 (128x128): 8 ot * 4 kb
  for (int idx = tid; idx < 16384; idx += stp) {
    int e = idx & 7, ln = (idx >> 3) & 63, f = idx >> 9;
    int kb = f & 3, ot = f >> 2;
    int k = kb * 32 + (ln >> 4) * 8 + e;
    int o = ot * 16 + (ln & 15);
    ws[idx] = f2bu(Wmix1[k * 128 + o]);
  }
  // B2: W1_1 (192x64): 4 ot * 6 kb, at ushort offset 16384
  for (int idx = tid; idx < 12288; idx += stp) {
    int e = idx & 7, ln = (idx >> 3) & 63, f = idx >> 9;
    int kb = f % 6, ot = f / 6;
    int k = kb * 32 + (ln >> 4) * 8 + e;
    int n = ot * 16 + (ln & 15);
    ws[16384 + idx] = f2bu(W1_1[k * 64 + n]);
  }
  // B3: W2_1 (64x128): 8 ot * 2 kb, at ushort offset 28672
  for (int idx = tid; idx < 8192; idx += stp) {
    int e = idx & 7, ln = (idx >> 3) & 63, f = idx >> 9;
    int kb = f & 1, ot = f >> 1;
    int k = kb * 32 + (ln >> 4) * 8 + e;
    int n = ot * 16 + (ln & 15);
    ws[28672 + idx] = f2bu(W2_1[k * 128 + n]);
  }
}

// ---------------- fused main kernel: one 16-atom job per wave ----------------
__global__ __launch_bounds__(256, 3)
void fused_kernel(const float* __restrict__ pos,
                  const float* __restrict__ srep,
                  const float* __restrict__ vrep,
                  const float4* __restrict__ wsf,
                  const float* __restrict__ b1_1,
                  const float* __restrict__ b2_1,
                  const float* __restrict__ Wmix2,
                  const float* __restrict__ W1_2,
                  const float* __restrict__ b1_2,
                  const float* __restrict__ W2_2,
                  const float* __restrict__ b2_2,
                  const float* __restrict__ Wd1,
                  const float* __restrict__ bd1,
                  const float* __restrict__ Wd2,
                  const float* __restrict__ bd2,
                  float* __restrict__ out) {
  __shared__ __align__(16) unsigned short smem[4 * 5120];  // 10 KiB per wave, wave-private
  const int tid  = threadIdx.x;
  const int lane = tid & 63;
  const int wv   = tid >> 6;
  const int r    = lane & 15;  // A row / D col index
  const int g    = lane >> 4;  // k-group / D row-group
  const int a0   = (blockIdx.x * 4 + wv) * 16;

  unsigned short* vWl = smem + wv * 5120;  // [3][16][64] bf16  (3072 ushorts)
  unsigned short* vVn = vWl + 3072;        // [16][64]          (1024)
  unsigned short* Hh  = vWl + 4096;        // [16][64]          (1024)
  unsigned short* SGl = vWl + 3072;        // [16][128] aliases vVn+Hh (safe: in-order DS, reads precede writes)

  // ============ GEMM1: vmix[3*16,128] = v * Wmix1 ============
  bf16x8 A1[3][4];
  {
    const float* vp = vrep + (size_t)(a0 + r) * 384;
#pragma unroll
    for (int c = 0; c < 3; ++c)
#pragma unroll
      for (int kb = 0; kb < 4; ++kb)
        A1[c][kb] = cvt8v(vp + c * 128 + kb * 32 + g * 8);
  }
#pragma unroll
  for (int ot = 0; ot < 8; ++ot) {
    bf16x8 B[4];
#pragma unroll
    for (int kb = 0; kb < 4; ++kb)
      B[kb] = ldfrag(wsf + (ot * 4 + kb) * 64 + lane);
    f32x4 ac0 = {0.f, 0.f, 0.f, 0.f}, ac1 = ac0, ac2 = ac0;
#pragma unroll
    for (int kb = 0; kb < 4; ++kb) {
      ac0 = __builtin_amdgcn_mfma_f32_16x16x32_bf16(A1[0][kb], B[kb], ac0, 0, 0, 0);
      ac1 = __builtin_amdgcn_mfma_f32_16x16x32_bf16(A1[1][kb], B[kb], ac1, 0, 0, 0);
      ac2 = __builtin_amdgcn_mfma_f32_16x16x32_bf16(A1[2][kb], B[kb], ac2, 0, 0, 0);
    }
    if (ot < 4) {  // vV half -> per-atom norm over c
#pragma unroll
      for (int i = 0; i < 4; ++i) {
        int row = g * 4 + i;
        float nv = sqrtf(ac0[i] * ac0[i] + ac1[i] * ac1[i] + ac2[i] * ac2[i]);
        vVn[row * 64 + SW(row, ot * 16 + r)] = f2bu(nv);
      }
    } else {  // vW half -> keep for gating
      int col = (ot - 4) * 16 + r;
#pragma unroll
      for (int i = 0; i < 4; ++i) {
        int row = g * 4 + i;
        int sc  = SW(row, col);
        vWl[       row * 64 + sc] = f2bu(ac0[i]);
        vWl[1024 + row * 64 + sc] = f2bu(ac1[i]);
        vWl[2048 + row * 64 + sc] = f2bu(ac2[i]);
      }
    }
  }

  // ============ GEMM2: x[16,64] = silu([s, vVn] * W1_1 + b1_1) ============
  bf16x8 A2[6];
  {
    const float* sp = srep + (size_t)(a0 + r) * 128;
#pragma unroll
    for (int kb = 0; kb < 4; ++kb)
      A2[kb] = cvt8v(sp + kb * 32 + g * 8);
#pragma unroll
    for (int kb = 0; kb < 2; ++kb) {
      int col0 = kb * 32 + g * 8;
      A2[4 + kb] = *reinterpret_cast<const bf16x8*>(vVn + r * 64 + SW(r, col0));
    }
  }
  float b1v[4];
#pragma unroll
  for (int ot = 0; ot < 4; ++ot) b1v[ot] = b1_1[ot * 16 + r];
#pragma unroll
  for (int ot = 0; ot < 4; ++ot) {
    bf16x8 B[6];
#pragma unroll
    for (int kb = 0; kb < 6; ++kb)
      B[kb] = ldfrag(wsf + 2048 + (ot * 6 + kb) * 64 + lane);
    f32x4 ac = {0.f, 0.f, 0.f, 0.f};
#pragma unroll
    for (int kb = 0; kb < 6; ++kb)
      ac = __builtin_amdgcn_mfma_f32_16x16x32_bf16(A2[kb], B[kb], ac, 0, 0, 0);
#pragma unroll
    for (int i = 0; i < 4; ++i) {
      int row = g * 4 + i;
      Hh[row * 64 + SW(row, ot * 16 + r)] = f2bu(fsilu(ac[i] + b1v[ot]));
    }
  }

  // ============ GEMM3: x2[16,128] = h * W2_1 + b2_1 ============
  bf16x8 A3[2];
#pragma unroll
  for (int kb = 0; kb < 2; ++kb) {
    int col0 = kb * 32 + g * 8;
    A3[kb] = *reinterpret_cast<const bf16x8*>(Hh + r * 64 + SW(r, col0));
  }
  float b2v[8];
#pragma unroll
  for (int ot = 0; ot < 8; ++ot) b2v[ot] = b2_1[ot * 16 + r];
#pragma unroll
  for (int ot = 0; ot < 8; ++ot) {
    bf16x8 B[2];
#pragma unroll
    for (int kb = 0; kb < 2; ++kb)
      B[kb] = ldfrag(wsf + 3584 + (ot * 2 + kb) * 64 + lane);
    f32x4 ac = {0.f, 0.f, 0.f, 0.f};
#pragma unroll
    for (int kb = 0; kb < 2; ++kb)
      ac = __builtin_amdgcn_mfma_f32_16x16x32_bf16(A3[kb], B[kb], ac, 0, 0, 0);
#pragma unroll
    for (int i = 0; i < 4; ++i) {
      int row = g * 4 + i;
      float x = ac[i] + b2v[ot];
      if (ot < 4) {
        SGl[row * 128 + SW(row, ot * 16 + r)] = f2bu(fsilu(x));        // s_out
      } else {
        SGl[row * 128 + SW(row, 64 + (ot - 4) * 16 + r)] = f2bu(x);    // gate
      }
    }
  }

  // ============ epilogue: block2 + final MLP, 4 lanes per atom ============
  const int aq   = lane >> 2;  // local atom 0..15
  const int q    = lane & 3;   // o'-quarter
  const int atom = a0 + aq;

  float p00 = 0.f, p01 = 0.f, p02 = 0.f, p10 = 0.f, p11 = 0.f, p12 = 0.f, sw = 0.f;
  const float2* Wm2 = reinterpret_cast<const float2*>(Wmix2);
#pragma unroll
  for (int h = 0; h < 2; ++h) {
    float so[8], ga[8], v0[8], v1[8], v2[8];
    int col = q * 16 + h * 8;
    ld8(SGl +        aq * 128 + SW(aq, col),      so);
    ld8(SGl +        aq * 128 + SW(aq, 64 + col), ga);
    ld8(vWl +        aq * 64  + SW(aq, col),      v0);
    ld8(vWl + 1024 + aq * 64  + SW(aq, col),      v1);
    ld8(vWl + 2048 + aq * 64  + SW(aq, col),      v2);
#pragma unroll
    for (int i = 0; i < 8; ++i) {
      int o = col + i;
      float2 wm = Wm2[o];
      float t0 = ga[i] * v0[i], t1 = ga[i] * v1[i], t2 = ga[i] * v2[i];
      p00 += t0 * wm.x; p01 += t1 * wm.x; p02 += t2 * wm.x;
      p10 += t0 * wm.y; p11 += t1 * wm.y; p12 += t2 * wm.y;
      sw  += so[i] * W1_2[o];
    }
  }
#pragma unroll
  for (int m = 1; m <= 2; m <<= 1) {
    p00 += __shfl_xor(p00, m); p01 += __shfl_xor(p01, m); p02 += __shfl_xor(p02, m);
    p10 += __shfl_xor(p10, m); p11 += __shfl_xor(p11, m); p12 += __shfl_xor(p12, m);
    sw  += __shfl_xor(sw,  m);
  }
  float vn2 = sqrtf(p00 * p00 + p01 * p01 + p02 * p02);
  float x1  = fsilu(sw + vn2 * W1_2[64] + b1_2[0]);
  float s2  = x1 * W2_2[0] + b2_2[0];
  float g2  = x1 * W2_2[1] + b2_2[1];
  float feat[7];
  feat[0] = g2 * p10; feat[1] = g2 * p11; feat[2] = g2 * p12;
  feat[3] = pos[atom * 3 + 0];
  feat[4] = pos[atom * 3 + 1];
  feat[5] = pos[atom * 3 + 2];
  feat[6] = s2;
  float o0 = bd2[0], o1 = bd2[1], o2 = bd2[2];
#pragma unroll
  for (int j = 0; j < 10; ++j) {
    float hp = bd1[j];
#pragma unroll
    for (int i = 0; i < 7; ++i) hp += feat[i] * Wd1[i * 10 + j];
    float hj = fsilu(hp);
    o0 += hj * Wd2[j * 3 + 0];
    o1 += hj * Wd2[j * 3 + 1];
    o2 += hj * Wd2[j * 3 + 2];
  }
  if (q < 3) {
    out[atom * 3 + q] = (q == 0) ? o0 : ((q == 1) ? o1 : o2);
  }
}

extern "C" void kernel_launch(void* const* d_in, const int* in_sizes, int n_in,
                              void* d_out, int out_size, void* d_ws, size_t ws_size,
                              hipStream_t stream) {
  const float* pos   = (const float*)d_in[0];
  const float* srep  = (const float*)d_in[1];
  const float* vrep  = (const float*)d_in[2];
  const float* Wmix1 = (const float*)d_in[4];
  const float* W1_1  = (const float*)d_in[5];
  const float* b1_1  = (const float*)d_in[6];
  const float* W2_1  = (const float*)d_in[7];
  const float* b2_1  = (const float*)d_in[8];
  const float* Wmix2 = (const float*)d_in[9];
  const float* W1_2  = (const float*)d_in[10];
  const float* b1_2  = (const float*)d_in[11];
  const float* W2_2  = (const float*)d_in[12];
  const float* b2_2  = (const float*)d_in[13];
  const float* Wd1   = (const float*)d_in[14];
  const float* bd1   = (const float*)d_in[15];
  const float* Wd2   = (const float*)d_in[16];
  const float* bd2   = (const float*)d_in[17];

  hipLaunchKernelGGL(prep_kernel, dim3(36), dim3(256), 0, stream,
                     Wmix1, W1_1, W2_1, (unsigned short*)d_ws);
  hipLaunchKernelGGL(fused_kernel, dim3(BLOCKS), dim3(256), 0, stream,
                     pos, srep, vrep, (const float4*)d_ws,
                     b1_1, b2_1, Wmix2, W1_2, b1_2, W2_2, b2_2,
                     Wd1, bd1, Wd2, bd2, (float*)d_out);
}